// Round 8
// baseline (604.099 us; speedup 1.0000x reference)
//
#include <hip/hip_runtime.h>
#include <stdint.h>

#define BATCH 2
#define QLEN 1024
#define KLEN 2048
#define NH 32
#define HD 128
#define HID 4096

typedef short bf16x8 __attribute__((ext_vector_type(8)));
typedef float f32x4 __attribute__((ext_vector_type(4)));
typedef unsigned short u16;

typedef const __attribute__((address_space(1))) void gvoid;
typedef __attribute__((address_space(3))) void lvoid;

__device__ __forceinline__ u16 f2bf(float f) {
  union { float f; uint32_t u; } x; x.f = f;
  uint32_t r = x.u + 0x7fffu + ((x.u >> 16) & 1u);
  return (u16)(r >> 16);
}
__device__ __forceinline__ float bf2f(u16 h) {
  union { uint32_t u; float f; } x; x.u = ((uint32_t)h) << 16;
  return x.f;
}
__device__ __forceinline__ f32x4 mfma16(bf16x8 a, bf16x8 b, f32x4 c) {
  return __builtin_amdgcn_mfma_f32_16x16x32_bf16(a, b, c, 0, 0, 0);
}
__device__ __forceinline__ void glds16(const u16* src, char* dst) {
  __builtin_amdgcn_global_load_lds((gvoid*)src, (lvoid*)dst, 16, 0, 0);
}

// ---------------- f32 -> bf16 convert, 8 elems/thread ----------------
__device__ __forceinline__ void cvt8(const float* in, u16* out, int i) {
  const float4* p = (const float4*)(in + i);
  float4 a = p[0], b = p[1];
  union { u16 h[8]; bf16x8 v; } u;
  u.h[0] = f2bf(a.x); u.h[1] = f2bf(a.y); u.h[2] = f2bf(a.z); u.h[3] = f2bf(a.w);
  u.h[4] = f2bf(b.x); u.h[5] = f2bf(b.y); u.h[6] = f2bf(b.z); u.h[7] = f2bf(b.w);
  *(bf16x8*)(out + i) = u.v;
}

__global__ __launch_bounds__(256) void cvt_kernel(const float* __restrict__ in,
                                                  u16* __restrict__ out, int n) {
  int i = (blockIdx.x * 256 + threadIdx.x) * 8;
  if (i >= n) return;
  cvt8(in, out, i);
}

// two-segment convert (segment sizes multiples of 8)
__global__ __launch_bounds__(256) void cvt2_kernel(const float* __restrict__ s0,
                                                   u16* __restrict__ d0, int n0,
                                                   const float* __restrict__ s1,
                                                   u16* __restrict__ d1, int n1) {
  int i = (blockIdx.x * 256 + threadIdx.x) * 8;
  if (i < n0) {
    cvt8(s0, d0, i);
  } else {
    int j = i - n0;
    if (j < n1) cvt8(s1, d1, j);
  }
}

// ================= shared 256x256 K-tile schedule (R5: even issue, counted vmcnt)
// LDS: A dbuf 2x32KB at [0,64K), B dbuf 2x32KB at [64K,128K).
// Per buffer: [k-half][row r 0..255][slot s][16B], phys slot s = g ^ ((r>>1)&3)
// -> conflict-free b128 reads (verified: SQ_LDS_BANK_CONFLICT = 0).
#define RD_A(CB, ks, mf) (*(const bf16x8*)(lds + (CB) + (ks) * 16384 + (mf) * 1024 + rA))
#define RD_B(CB, ks, nf) (*(const bf16x8*)(lds + 65536 + (CB) + (ks) * 16384 + (nf) * 1024 + rB))

#define TILE256(CB, NB, K0N)                                                     \
  {                                                                              \
    bf16x8 af[4], bfr[4], af2[4];                                                \
    _Pragma("unroll") for (int x = 0; x < 4; x++) af[x] = RD_A(CB, 0, x);        \
    _Pragma("unroll") for (int x = 0; x < 4; x++) bfr[x] = RD_B(CB, 0, x);       \
    glds16(As0 + (K0N), dA + (NB));                                              \
    glds16(As1 + (K0N), dA + (NB) + 8192);                                       \
    __builtin_amdgcn_s_barrier();                                                \
    asm volatile("s_waitcnt lgkmcnt(0)" ::: "memory");                           \
    __builtin_amdgcn_sched_barrier(0);                                           \
    __builtin_amdgcn_s_setprio(1);                                               \
    _Pragma("unroll") for (int mf = 0; mf < 4; mf++)                             \
      _Pragma("unroll") for (int nf = 0; nf < 4; nf++)                           \
        acc[mf][nf] = mfma16(af[mf], bfr[nf], acc[mf][nf]);                      \
    __builtin_amdgcn_s_setprio(0);                                               \
    __builtin_amdgcn_s_barrier();                                                \
    _Pragma("unroll") for (int x = 0; x < 4; x++) af2[x] = RD_A(CB, 0, 4 + x);   \
    glds16(Bs0 + (K0N), dB + (NB));                                              \
    glds16(Bs1 + (K0N), dB + (NB) + 8192);                                       \
    asm volatile("s_waitcnt vmcnt(4)" ::: "memory");                             \
    __builtin_amdgcn_s_barrier();                                                \
    asm volatile("s_waitcnt lgkmcnt(0)" ::: "memory");                           \
    __builtin_amdgcn_sched_barrier(0);                                           \
    __builtin_amdgcn_s_setprio(1);                                               \
    _Pragma("unroll") for (int mf = 0; mf < 4; mf++)                             \
      _Pragma("unroll") for (int nf = 0; nf < 4; nf++)                           \
        acc[4 + mf][nf] = mfma16(af2[mf], bfr[nf], acc[4 + mf][nf]);             \
    __builtin_amdgcn_s_setprio(0);                                               \
    __builtin_amdgcn_s_barrier();                                                \
    _Pragma("unroll") for (int x = 0; x < 4; x++) af[x] = RD_A(CB, 1, x);        \
    _Pragma("unroll") for (int x = 0; x < 4; x++) bfr[x] = RD_B(CB, 1, x);       \
    glds16(As0 + (K0N) + 32, dA + (NB) + 16384);                                 \
    glds16(As1 + (K0N) + 32, dA + (NB) + 16384 + 8192);                          \
    __builtin_amdgcn_s_barrier();                                                \
    asm volatile("s_waitcnt lgkmcnt(0)" ::: "memory");                           \
    __builtin_amdgcn_sched_barrier(0);                                           \
    __builtin_amdgcn_s_setprio(1);                                               \
    _Pragma("unroll") for (int mf = 0; mf < 4; mf++)                             \
      _Pragma("unroll") for (int nf = 0; nf < 4; nf++)                           \
        acc[mf][nf] = mfma16(af[mf], bfr[nf], acc[mf][nf]);                      \
    __builtin_amdgcn_s_setprio(0);                                               \
    __builtin_amdgcn_s_barrier();                                                \
    _Pragma("unroll") for (int x = 0; x < 4; x++) af2[x] = RD_A(CB, 1, 4 + x);   \
    glds16(Bs0 + (K0N) + 32, dB + (NB) + 16384);                                 \
    glds16(Bs1 + (K0N) + 32, dB + (NB) + 16384 + 8192);                          \
    asm volatile("s_waitcnt vmcnt(4)" ::: "memory");                             \
    __builtin_amdgcn_s_barrier();                                                \
    asm volatile("s_waitcnt lgkmcnt(0)" ::: "memory");                           \
    __builtin_amdgcn_sched_barrier(0);                                           \
    __builtin_amdgcn_s_setprio(1);                                               \
    _Pragma("unroll") for (int mf = 0; mf < 4; mf++)                             \
      _Pragma("unroll") for (int nf = 0; nf < 4; nf++)                           \
        acc[4 + mf][nf] = mfma16(af2[mf], bfr[nf], acc[4 + mf][nf]);             \
    __builtin_amdgcn_s_setprio(0);                                               \
    __builtin_amdgcn_s_barrier();                                                \
  }

// ============ fused K+V projection GEMM ============
// A = kv activations [4096][4096] bf16 (m-tiled by 256)
// Bw = stacked weights [Wk; Wv] = [8192][4096] bf16 (n-tiled by 256)
// n0g < 4096 -> K half: Ck[m][n] bf16 row-major (N=4096)
// n0g >= 4096 -> V half: Cvt in VT layout ((bb*4096+colv)*2048 + tt)
__global__ __launch_bounds__(512, 2) void gemm256kv(const u16* __restrict__ A,
                                                    const u16* __restrict__ Bw,
                                                    u16* __restrict__ Ck,
                                                    u16* __restrict__ Cvt) {
  const int K = HID;
  __shared__ alignas(16) char lds[131072];
  const int tid = threadIdx.x;
  const int lane = tid & 63, wv = tid >> 6;
  const int wvm = wv >> 2, wvn = wv & 3;
  const int g = lane >> 4, l16 = lane & 15;

  // XCD-aware bijective swizzle (nwg = 512)
  const int lin = blockIdx.y * 32 + blockIdx.x;
  const int swz = (lin & 7) * 64 + (lin >> 3);
  const int m0 = (swz >> 5) * 256;
  const int n0g = (swz & 31) * 256;

  const int srow = tid >> 2;
  const int sg = (tid & 3) ^ ((srow >> 1) & 3);
  const u16* As0 = A + (size_t)(m0 + srow) * K + sg * 8;
  const u16* As1 = A + (size_t)(m0 + 128 + srow) * K + sg * 8;
  const u16* Bs0 = Bw + (size_t)(n0g + srow) * K + sg * 8;
  const u16* Bs1 = Bw + (size_t)(n0g + 128 + srow) * K + sg * 8;
  char* dA = lds + tid * 16;
  char* dB = lds + 65536 + tid * 16;

  const int rsw = (g ^ ((l16 >> 1) & 3)) << 4;
  const int rA = (wvm * 128 + l16) * 64 + rsw;
  const int rB = (wvn * 64 + l16) * 64 + rsw;

  f32x4 acc[8][4];
#pragma unroll
  for (int mf = 0; mf < 8; mf++)
#pragma unroll
    for (int nf = 0; nf < 4; nf++) acc[mf][nf] = (f32x4){0.f, 0.f, 0.f, 0.f};

  glds16(As0, dA);
  glds16(As1, dA + 8192);
  glds16(Bs0, dB);
  glds16(Bs1, dB + 8192);
  glds16(As0 + 32, dA + 16384);
  glds16(As1 + 32, dA + 16384 + 8192);
  glds16(Bs0 + 32, dB + 16384);
  glds16(Bs1 + 32, dB + 16384 + 8192);
  asm volatile("s_waitcnt vmcnt(4)" ::: "memory");
  __builtin_amdgcn_s_barrier();

  const int NT = K >> 6;
  for (int t = 0; t < NT; t += 2) {
    const int kA = (t + 1) * 64;
    TILE256(0, 32768, kA)
    const int kB = (((t + 2) < NT) ? (t + 2) : 0) * 64;
    TILE256(32768, 0, kB)
  }

  if (n0g < 4096) {  // K half: bf16 row-major
#pragma unroll
    for (int mf = 0; mf < 8; mf++) {
      int rowb = m0 + wvm * 128 + mf * 16 + g * 4;
#pragma unroll
      for (int nf = 0; nf < 4; nf++) {
        int col = n0g + wvn * 64 + nf * 16 + l16;
#pragma unroll
        for (int j = 0; j < 4; j++)
          Ck[(size_t)(rowb + j) * HID + col] = f2bf(acc[mf][nf][j]);
      }
    }
  } else {  // V half: VT layout
#pragma unroll
    for (int mf = 0; mf < 8; mf++) {
      int rowb = m0 + wvm * 128 + mf * 16 + g * 4;
      int bb = rowb >> 11, tt = rowb & 2047;
#pragma unroll
      for (int nf = 0; nf < 4; nf++) {
        int colv = (n0g - 4096) + wvn * 64 + nf * 16 + l16;
        uint64_t pk = (uint64_t)f2bf(acc[mf][nf][0]) |
                      ((uint64_t)f2bf(acc[mf][nf][1]) << 16) |
                      ((uint64_t)f2bf(acc[mf][nf][2]) << 32) |
                      ((uint64_t)f2bf(acc[mf][nf][3]) << 48);
        *(uint64_t*)(Cvt + ((size_t)(bb * 4096 + colv)) * 2048 + tt) = pk;
      }
    }
  }
}

// ============ 256x128 transposed-output GEMM, TRIPLE-buffered ============
// A = weights [4096][4096] (M-tiled by 256), Bact = activations [2048][4096]
// (N-tiled by 128). out[act][feature] written transposed vs accumulator.
// EPI 0: f32 out; EPI 2: bf16 out. Grid (16,16) = 256 blocks.
#define RD_AT(BUF, ks, mf) \
  (*(const bf16x8*)(lds + (BUF) * 32768 + (ks) * 16384 + (mf) * 1024 + rA))
#define RD_BT(BUF, ks, nf) \
  (*(const bf16x8*)(lds + 98304 + (BUF) * 16384 + (ks) * 8192 + (nf) * 1024 + rB))

#define STG_H0(BUF, K0N)                                    \
  glds16(AsT0 + (K0N), dAT + (BUF) * 32768);                \
  glds16(AsT1 + (K0N), dAT + (BUF) * 32768 + 8192);         \
  glds16(BsT0 + (K0N), dBT + (BUF) * 16384);

#define STG_H1(BUF, K0N)                                    \
  glds16(AsT0 + (K0N) + 32, dAT + (BUF) * 32768 + 16384);   \
  glds16(AsT1 + (K0N) + 32, dAT + (BUF) * 32768 + 16384 + 8192); \
  glds16(BsT0 + (K0N) + 32, dBT + (BUF) * 16384 + 8192);

#define TILE256T(CUR, STG, K0N)                                                  \
  {                                                                              \
    bf16x8 af[4], bfr[4];                                                        \
    _Pragma("unroll") for (int x = 0; x < 4; x++) af[x] = RD_AT(CUR, 0, x);      \
    _Pragma("unroll") for (int x = 0; x < 4; x++) bfr[x] = RD_BT(CUR, 0, x);     \
    STG_H0(STG, K0N)                                                             \
    __builtin_amdgcn_s_barrier();                                                \
    asm volatile("s_waitcnt lgkmcnt(0)" ::: "memory");                           \
    __builtin_amdgcn_sched_barrier(0);                                           \
    __builtin_amdgcn_s_setprio(1);                                               \
    _Pragma("unroll") for (int mf = 0; mf < 4; mf++)                             \
      _Pragma("unroll") for (int nf = 0; nf < 4; nf++)                           \
        acc[mf][nf] = mfma16(af[mf], bfr[nf], acc[mf][nf]);                      \
    __builtin_amdgcn_s_setprio(0);                                               \
    __builtin_amdgcn_s_barrier();                                                \
    _Pragma("unroll") for (int x = 0; x < 4; x++) af[x] = RD_AT(CUR, 1, x);      \
    _Pragma("unroll") for (int x = 0; x < 4; x++) bfr[x] = RD_BT(CUR, 1, x);     \
    STG_H1(STG, K0N)                                                             \
    asm volatile("s_waitcnt vmcnt(6)" ::: "memory");                             \
    __builtin_amdgcn_s_barrier();                                                \
    asm volatile("s_waitcnt lgkmcnt(0)" ::: "memory");                           \
    __builtin_amdgcn_sched_barrier(0);                                           \
    __builtin_amdgcn_s_setprio(1);                                               \
    _Pragma("unroll") for (int mf = 0; mf < 4; mf++)                             \
      _Pragma("unroll") for (int nf = 0; nf < 4; nf++)                           \
        acc[mf][nf] = mfma16(af[mf], bfr[nf], acc[mf][nf]);                      \
    __builtin_amdgcn_s_setprio(0);                                               \
    __builtin_amdgcn_s_barrier();                                                \
  }

template <int EPI>
__global__ __launch_bounds__(512, 2) void gemm256T(const u16* __restrict__ W,
                                                   const u16* __restrict__ Act,
                                                   void* __restrict__ Cout) {
  const int K = HID;       // NT = 64 = 21*3 + 1 tail
  __shared__ alignas(16) char lds[147456];
  const int tid = threadIdx.x;
  const int lane = tid & 63, wv = tid >> 6;
  const int wvm = wv >> 1, wvn = wv & 1;  // 4 x 2 waves, each 64x64
  const int g = lane >> 4, l16 = lane & 15;

  const int lin = blockIdx.y * 16 + blockIdx.x;
  const int swz = (lin & 7) * 32 + (lin >> 3);
  const int m0 = (swz >> 4) * 256;     // feature tile
  const int n0 = (swz & 15) * 128;     // activation tile

  const int srow = tid >> 2;
  const int sg = (tid & 3) ^ ((srow >> 1) & 3);
  const u16* AsT0 = W + (size_t)(m0 + srow) * K + sg * 8;
  const u16* AsT1 = W + (size_t)(m0 + 128 + srow) * K + sg * 8;
  const u16* BsT0 = Act + (size_t)(n0 + srow) * K + sg * 8;
  char* dAT = lds + tid * 16;
  char* dBT = lds + 98304 + tid * 16;

  const int rsw = (g ^ ((l16 >> 1) & 3)) << 4;
  const int rA = (wvm * 64 + l16) * 64 + rsw;
  const int rB = (wvn * 64 + l16) * 64 + rsw;

  f32x4 acc[4][4];
#pragma unroll
  for (int mf = 0; mf < 4; mf++)
#pragma unroll
    for (int nf = 0; nf < 4; nf++) acc[mf][nf] = (f32x4){0.f, 0.f, 0.f, 0.f};

  STG_H0(0, 0)
  STG_H1(0, 0)
  STG_H0(1, 64)
  STG_H1(1, 64)
  asm volatile("s_waitcnt vmcnt(6)" ::: "memory");
  __builtin_amdgcn_s_barrier();

  for (int t = 0; t < 63; t += 3) {
    const int k1 = (t + 2) * 64;
    const int k2 = (t + 3) * 64;
    const int k3 = ((t + 4) < 64) ? (t + 4) * 64 : 0;
    TILE256T(0, 2, k1)
    TILE256T(1, 0, k2)
    TILE256T(2, 1, k3)
  }
  {
    bf16x8 af[4], bfr[4];
#pragma unroll
    for (int x = 0; x < 4; x++) af[x] = RD_AT(0, 0, x);
#pragma unroll
    for (int x = 0; x < 4; x++) bfr[x] = RD_BT(0, 0, x);
#pragma unroll
    for (int mf = 0; mf < 4; mf++)
#pragma unroll
      for (int nf = 0; nf < 4; nf++)
        acc[mf][nf] = mfma16(af[mf], bfr[nf], acc[mf][nf]);
#pragma unroll
    for (int x = 0; x < 4; x++) af[x] = RD_AT(0, 1, x);
#pragma unroll
    for (int x = 0; x < 4; x++) bfr[x] = RD_BT(0, 1, x);
#pragma unroll
    for (int mf = 0; mf < 4; mf++)
#pragma unroll
      for (int nf = 0; nf < 4; nf++)
        acc[mf][nf] = mfma16(af[mf], bfr[nf], acc[mf][nf]);
  }

  if (EPI == 0) {
    float* C = (float*)Cout;
#pragma unroll
    for (int mf = 0; mf < 4; mf++) {
      int frow = m0 + wvm * 64 + mf * 16 + g * 4;
#pragma unroll
      for (int nf = 0; nf < 4; nf++) {
        int col = n0 + wvn * 64 + nf * 16 + l16;
        float4 v = {acc[mf][nf][0], acc[mf][nf][1], acc[mf][nf][2], acc[mf][nf][3]};
        *(float4*)(C + (size_t)col * HID + frow) = v;
      }
    }
  } else {
    u16* C = (u16*)Cout;
#pragma unroll
    for (int mf = 0; mf < 4; mf++) {
      int frow = m0 + wvm * 64 + mf * 16 + g * 4;
#pragma unroll
      for (int nf = 0; nf < 4; nf++) {
        int col = n0 + wvn * 64 + nf * 16 + l16;
        uint64_t pk = (uint64_t)f2bf(acc[mf][nf][0]) |
                      ((uint64_t)f2bf(acc[mf][nf][1]) << 16) |
                      ((uint64_t)f2bf(acc[mf][nf][2]) << 32) |
                      ((uint64_t)f2bf(acc[mf][nf][3]) << 48);
        *(uint64_t*)(C + (size_t)col * HID + frow) = pk;
      }
    }
  }
}

// ---------------- fused RoPE(Q) + RoPE(K) + vmean ----------------
// blocks [0,2048): Q rows; [2048,6144): K rows; [6144,8192): vmean
__device__ __forceinline__ void rope_row(const u16* x, float p, u16* out,
                                         int rowsPerB, int row, int t) {
  int b = row / rowsPerB, r = row - b * rowsPerB;
  int h = t >> 3, i0 = (t & 7) * 8;
  const u16* xr = x + (size_t)row * HID + h * HD;
  bf16x8 lov = *(const bf16x8*)(xr + i0);
  bf16x8 hiv = *(const bf16x8*)(xr + 64 + i0);
  union { u16 h[8]; bf16x8 v; } olo, ohi;
#pragma unroll
  for (int j = 0; j < 8; j++) {
    float lo = bf2f((u16)lov[j]);
    float hi = bf2f((u16)hiv[j]);
    float f = exp2f(-(float)(i0 + j) * (13.287712379549449f / 64.0f));
    float ang = p * f;
    float s, c;
    sincosf(ang, &s, &c);
    olo.h[j] = f2bf(lo * c - hi * s);
    ohi.h[j] = f2bf(hi * c + lo * s);
  }
  u16* ob = out + ((size_t)((b * NH + h) * rowsPerB) + r) * HD;
  *(bf16x8*)(ob + i0) = olo.v;
  *(bf16x8*)(ob + 64 + i0) = ohi.v;
}

__global__ __launch_bounds__(256) void rope_vmean_kernel(
    const u16* __restrict__ qsrc, const u16* __restrict__ ksrc,
    u16* __restrict__ qdst, u16* __restrict__ kdst,
    const int* __restrict__ pos, const int* __restrict__ tpos,
    const u16* __restrict__ vt, float* __restrict__ vm) {
  int bid = blockIdx.x;
  if (bid >= 6144) {
    int row = (bid - 6144) * 4 + (threadIdx.x >> 6);
    int lane = threadIdx.x & 63;
    const u16* p = vt + (size_t)row * KLEN;
    float s = 0.f;
#pragma unroll
    for (int it = 0; it < 4; it++) {
      bf16x8 v = *(const bf16x8*)(p + it * 512 + lane * 8);
#pragma unroll
      for (int j = 0; j < 8; j++) s += bf2f((u16)v[j]);
    }
    for (int off = 32; off; off >>= 1) s += __shfl_xor(s, off);
    if (lane == 0) vm[row] = s * (1.0f / (float)KLEN);
    return;
  }
  if (bid < 2048) {
    rope_row(qsrc, (float)pos[bid], qdst, QLEN, bid, threadIdx.x);
  } else {
    int row = bid - 2048;
    rope_row(ksrc, (float)tpos[row], kdst, KLEN, row, threadIdx.x);
  }
}

// ---------------- windowed flash attention ----------------
__global__ __launch_bounds__(256, 2) void attn_kernel(
    const u16* __restrict__ qb, const u16* __restrict__ kb,
    const u16* __restrict__ vt, const float* __restrict__ vm,
    const int* __restrict__ idxA, const int* __restrict__ wA,
    u16* __restrict__ aout) {
  __shared__ u16 Ks[32][136];
  __shared__ u16 Vs[128][40];
  __shared__ u16 Ps[4][16][40];
  __shared__ int sS[64], sE[64], sRange[2];

  const int tid = threadIdx.x, lane = tid & 63, wv = tid >> 6;
  const int g = lane >> 4, l16 = lane & 15;
  const int blk = blockIdx.x;
  const int qt = blk & 15, bh = blk >> 4, b = bh >> 5, h = bh & 31;
  const int q0 = qt * 64;
  const float SCALE = 0.08838834764831845f;

  if (tid < 64) {
    int e = idxA[b * QLEN + q0 + tid];
    int w = wA[b * QLEN + q0 + tid];
    int s = e - w;
    if (s < 0) s = 0;
    sS[tid] = s;
    sE[tid] = e;
  }
  __syncthreads();
  if (wv == 0) {
    int s_ = sS[lane], e_ = sE[lane];
    int mn = (e_ > s_) ? s_ : 0x7fffffff;
    int mx = (e_ > s_) ? e_ : 0;
    for (int off = 32; off; off >>= 1) {
      mn = min(mn, __shfl_xor(mn, off));
      mx = max(mx, __shfl_xor(mx, off));
    }
    if (lane == 0) { sRange[0] = mn; sRange[1] = mx; }
  }
  __syncthreads();
  const int klo = sRange[0], khi = sRange[1];

  int rs[4], re[4];
#pragma unroll
  for (int r = 0; r < 4; r++) {
    rs[r] = sS[wv * 16 + g * 4 + r];
    re[r] = sE[wv * 16 + g * 4 + r];
  }

  bf16x8 qf[4];
  {
    const u16* qp = qb + ((size_t)(bh * QLEN + q0 + wv * 16 + l16)) * HD + g * 8;
#pragma unroll
    for (int s4 = 0; s4 < 4; s4++) qf[s4] = *(const bf16x8*)(qp + s4 * 32);
  }

  f32x4 acc[8];
#pragma unroll
  for (int db = 0; db < 8; db++) acc[db] = (f32x4){0.f, 0.f, 0.f, 0.f};
  float mrow[4] = {-1e30f, -1e30f, -1e30f, -1e30f};
  float lsum[4] = {0.f, 0.f, 0.f, 0.f};

  if (klo < khi) {
    for (int t0 = (klo & ~31); t0 < khi; t0 += 32) {
      {
        int idx = tid * 8;
        int kr = idx >> 7, kc = idx & 127;
        *(bf16x8*)(&Ks[kr][kc]) =
            *(const bf16x8*)(kb + ((size_t)(bh * KLEN + t0 + kr)) * HD + kc);
        int kr2 = kr + 16;
        *(bf16x8*)(&Ks[kr2][kc]) =
            *(const bf16x8*)(kb + ((size_t)(bh * KLEN + t0 + kr2)) * HD + kc);
        int vr = idx >> 5, vc = idx & 31;
        *(bf16x8*)(&Vs[vr][vc]) =
            *(const bf16x8*)(vt + ((size_t)(bh * HD + vr)) * KLEN + t0 + vc);
        int vr2 = vr + 64;
        *(bf16x8*)(&Vs[vr2][vc]) =
            *(const bf16x8*)(vt + ((size_t)(bh * HD + vr2)) * KLEN + t0 + vc);
      }
      __syncthreads();

      f32x4 sc0 = (f32x4){0.f, 0.f, 0.f, 0.f};
      f32x4 sc1 = (f32x4){0.f, 0.f, 0.f, 0.f};
#pragma unroll
      for (int s4 = 0; s4 < 4; s4++) {
        bf16x8 k0 = *(const bf16x8*)(&Ks[l16][s4 * 32 + g * 8]);
        bf16x8 k1 = *(const bf16x8*)(&Ks[16 + l16][s4 * 32 + g * 8]);
        sc0 = mfma16(qf[s4], k0, sc0);
        sc1 = mfma16(qf[s4], k1, sc1);
      }

      float resc[4];
#pragma unroll
      for (int r = 0; r < 4; r++) {
        float v0 = sc0[r] * SCALE, v1 = sc1[r] * SCALE;
        int t_0 = t0 + l16, t_1 = t0 + 16 + l16;
        v0 = (t_0 >= rs[r] && t_0 < re[r]) ? v0 : -1e30f;
        v1 = (t_1 >= rs[r] && t_1 < re[r]) ? v1 : -1e30f;
        float mx = fmaxf(v0, v1);
        mx = fmaxf(mx, __shfl_xor(mx, 1));
        mx = fmaxf(mx, __shfl_xor(mx, 2));
        mx = fmaxf(mx, __shfl_xor(mx, 4));
        mx = fmaxf(mx, __shfl_xor(mx, 8));
        float mn = fmaxf(mrow[r], mx);
        float rc = __expf(mrow[r] - mn);
        float p0 = __expf(v0 - mn), p1 = __expf(v1 - mn);
        mrow[r] = mn;
        resc[r] = rc;
        float ps = p0 + p1;
        ps += __shfl_xor(ps, 1);
        ps += __shfl_xor(ps, 2);
        ps += __shfl_xor(ps, 4);
        ps += __shfl_xor(ps, 8);
        lsum[r] = lsum[r] * rc + ps;
        Ps[wv][g * 4 + r][l16] = f2bf(p0);
        Ps[wv][g * 4 + r][16 + l16] = f2bf(p1);
      }
#pragma unroll
      for (int db = 0; db < 8; db++) {
#pragma unroll
        for (int r = 0; r < 4; r++) acc[db][r] *= resc[r];
      }
      bf16x8 pf = *(const bf16x8*)(&Ps[wv][l16][g * 8]);
#pragma unroll
      for (int db = 0; db < 8; db++) {
        bf16x8 vf = *(const bf16x8*)(&Vs[db * 16 + l16][g * 8]);
        acc[db] = mfma16(pf, vf, acc[db]);
      }
      __syncthreads();
    }
  }

#pragma unroll
  for (int r = 0; r < 4; r++) {
    int lr = wv * 16 + g * 4 + r;
    int q = q0 + lr;
    bool empty = (re[r] <= rs[r]);
    float inv = empty ? 0.f : 1.0f / lsum[r];
    u16* orow = aout + ((size_t)(b * QLEN + q)) * HID + h * HD;
#pragma unroll
    for (int db = 0; db < 8; db++) {
      float o = empty ? vm[bh * HD + db * 16 + l16] : acc[db][r] * inv;
      orow[db * 16 + l16] = f2bf(o);
    }
  }
}

// ---------------- host ----------------
extern "C" void kernel_launch(void* const* d_in, const int* in_sizes, int n_in,
                              void* d_out, int out_size, void* d_ws, size_t ws_size,
                              hipStream_t stream) {
  (void)in_sizes; (void)n_in; (void)out_size; (void)ws_size;
  const float* hs = (const float*)d_in[0];
  const float* kvs = (const float*)d_in[1];
  const float* Wq = (const float*)d_in[2];
  const float* Wk = (const float*)d_in[3];
  const float* Wv = (const float*)d_in[4];
  const float* Wo = (const float*)d_in[5];
  const int* pos = (const int*)d_in[6];
  const int* tpos = (const int*)d_in[7];
  const int* sidx = (const int*)d_in[8];
  const int* wsz = (const int*)d_in[9];
  float* out = (float*)d_out;

  char* ws = (char*)d_ws;
  size_t off = 0;
  auto alloc = [&](size_t bytes) -> void* {
    void* p = ws + off;
    off += (bytes + 255) & ~(size_t)255;
    return p;
  };
  const size_t WN = (size_t)HID * HID;           // 16.78M elems
  const size_t NQ = (size_t)BATCH * QLEN * HID;  // 8.39M
  const size_t NK = (size_t)BATCH * KLEN * HID;  // 16.78M

  // ~252 MB total
  u16* wbig = (u16*)alloc(2 * WN * 2);   // [Wk;Wv] stacked; first half reused for Wq/Wo
  u16* hid_b = (u16*)alloc(NQ * 2);
  u16* kv_b = (u16*)alloc(NK * 2);
  u16* sc_b = (u16*)alloc(NK * 2);       // K-proj out, later attn out
  u16* qp_b = (u16*)alloc(NQ * 2);       // Q-proj out
  u16* q_b = (u16*)alloc(NQ * 2);
  u16* k_b = (u16*)alloc(NK * 2);
  u16* vt_b = (u16*)alloc(NK * 2);
  float* vmean = (float*)alloc((size_t)BATCH * NH * HD * 4);

  // 1. both activations -> bf16
  cvt2_kernel<<<(int)((NQ + NK) / 2048), 256, 0, stream>>>(hs, hid_b, (int)NQ,
                                                           kvs, kv_b, (int)NK);
  // 2-3. Q projection
  cvt_kernel<<<(int)(WN / 2048), 256, 0, stream>>>(Wq, wbig, (int)WN);
  gemm256T<2><<<dim3(16, 16), 512, 0, stream>>>(wbig, hid_b, qp_b);

  // 4-5. fused K+V projection
  cvt2_kernel<<<(int)(2 * WN / 2048), 256, 0, stream>>>(Wk, wbig, (int)WN,
                                                        Wv, wbig + WN, (int)WN);
  gemm256kv<<<dim3(32, 16), 512, 0, stream>>>(kv_b, wbig, sc_b, vt_b);

  // 6. RoPE(Q) + RoPE(K) + vmean
  rope_vmean_kernel<<<8192, 256, 0, stream>>>(qp_b, sc_b, q_b, k_b, pos, tpos,
                                              vt_b, vmean);

  // 7. attention -> bf16 [B,Q,HID] into sc_b
  attn_kernel<<<BATCH * NH * (QLEN / 64), 256, 0, stream>>>(
      q_b, k_b, vt_b, vmean, sidx, wsz, sc_b);

  // 8-9. output projection -> f32 d_out
  cvt_kernel<<<(int)(WN / 2048), 256, 0, stream>>>(Wo, wbig, (int)WN);
  gemm256T<0><<<dim3(16, 16), 512, 0, stream>>>(wbig, sc_b, out);
}

// Round 9
// 564.189 us; speedup vs baseline: 1.0707x; 1.0707x over previous
//
#include <hip/hip_runtime.h>
#include <stdint.h>

#define BATCH 2
#define QLEN 1024
#define KLEN 2048
#define NH 32
#define HD 128
#define HID 4096

typedef short bf16x8 __attribute__((ext_vector_type(8)));
typedef float f32x4 __attribute__((ext_vector_type(4)));
typedef unsigned short u16;

typedef const __attribute__((address_space(1))) void gvoid;
typedef __attribute__((address_space(3))) void lvoid;

__device__ __forceinline__ u16 f2bf(float f) {
  union { float f; uint32_t u; } x; x.f = f;
  uint32_t r = x.u + 0x7fffu + ((x.u >> 16) & 1u);
  return (u16)(r >> 16);
}
__device__ __forceinline__ float bf2f(u16 h) {
  union { uint32_t u; float f; } x; x.u = ((uint32_t)h) << 16;
  return x.f;
}
__device__ __forceinline__ f32x4 mfma16(bf16x8 a, bf16x8 b, f32x4 c) {
  return __builtin_amdgcn_mfma_f32_16x16x32_bf16(a, b, c, 0, 0, 0);
}
__device__ __forceinline__ void glds16(const u16* src, char* dst) {
  __builtin_amdgcn_global_load_lds((gvoid*)src, (lvoid*)dst, 16, 0, 0);
}

// ---------------- f32 -> bf16 convert, 8 elems/thread ----------------
__device__ __forceinline__ void cvt8(const float* in, u16* out, int i) {
  const float4* p = (const float4*)(in + i);
  float4 a = p[0], b = p[1];
  union { u16 h[8]; bf16x8 v; } u;
  u.h[0] = f2bf(a.x); u.h[1] = f2bf(a.y); u.h[2] = f2bf(a.z); u.h[3] = f2bf(a.w);
  u.h[4] = f2bf(b.x); u.h[5] = f2bf(b.y); u.h[6] = f2bf(b.z); u.h[7] = f2bf(b.w);
  *(bf16x8*)(out + i) = u.v;
}

__global__ __launch_bounds__(256) void cvt_kernel(const float* __restrict__ in,
                                                  u16* __restrict__ out, int n) {
  int i = (blockIdx.x * 256 + threadIdx.x) * 8;
  if (i >= n) return;
  cvt8(in, out, i);
}

// two-segment convert (segment sizes multiples of 8)
__global__ __launch_bounds__(256) void cvt2_kernel(const float* __restrict__ s0,
                                                   u16* __restrict__ d0, int n0,
                                                   const float* __restrict__ s1,
                                                   u16* __restrict__ d1, int n1) {
  int i = (blockIdx.x * 256 + threadIdx.x) * 8;
  if (i < n0) {
    cvt8(s0, d0, i);
  } else {
    int j = i - n0;
    if (j < n1) cvt8(s1, d1, j);
  }
}

// ================= 256x256 GEMM (R5 schedule: even issue, counted vmcnt) ======
// C[M][N] = A[M][K] * Bw[N][K]^T, bf16 in.
// EPI 1: bf16 VT layout; EPI 2: bf16 row-major.
// LDS: A dbuf 2x32KB at [0,64K), B dbuf 2x32KB at [64K,128K).
// Per buffer: [k-half][row r 0..255][slot s][16B], phys slot s = g ^ ((r>>1)&3)
// -> conflict-free b128 reads (verified: SQ_LDS_BANK_CONFLICT = 0).
#define RD_A(CB, ks, mf) (*(const bf16x8*)(lds + (CB) + (ks) * 16384 + (mf) * 1024 + rA))
#define RD_B(CB, ks, nf) (*(const bf16x8*)(lds + 65536 + (CB) + (ks) * 16384 + (nf) * 1024 + rB))

#define TILE256(CB, NB, K0N)                                                     \
  {                                                                              \
    bf16x8 af[4], bfr[4], af2[4];                                                \
    _Pragma("unroll") for (int x = 0; x < 4; x++) af[x] = RD_A(CB, 0, x);        \
    _Pragma("unroll") for (int x = 0; x < 4; x++) bfr[x] = RD_B(CB, 0, x);       \
    glds16(As0 + (K0N), dA + (NB));                                              \
    glds16(As1 + (K0N), dA + (NB) + 8192);                                       \
    __builtin_amdgcn_s_barrier();                                                \
    asm volatile("s_waitcnt lgkmcnt(0)" ::: "memory");                           \
    __builtin_amdgcn_sched_barrier(0);                                           \
    __builtin_amdgcn_s_setprio(1);                                               \
    _Pragma("unroll") for (int mf = 0; mf < 4; mf++)                             \
      _Pragma("unroll") for (int nf = 0; nf < 4; nf++)                           \
        acc[mf][nf] = mfma16(af[mf], bfr[nf], acc[mf][nf]);                      \
    __builtin_amdgcn_s_setprio(0);                                               \
    __builtin_amdgcn_s_barrier();                                                \
    _Pragma("unroll") for (int x = 0; x < 4; x++) af2[x] = RD_A(CB, 0, 4 + x);   \
    glds16(Bs0 + (K0N), dB + (NB));                                              \
    glds16(Bs1 + (K0N), dB + (NB) + 8192);                                       \
    asm volatile("s_waitcnt vmcnt(4)" ::: "memory");                             \
    __builtin_amdgcn_s_barrier();                                                \
    asm volatile("s_waitcnt lgkmcnt(0)" ::: "memory");                           \
    __builtin_amdgcn_sched_barrier(0);                                           \
    __builtin_amdgcn_s_setprio(1);                                               \
    _Pragma("unroll") for (int mf = 0; mf < 4; mf++)                             \
      _Pragma("unroll") for (int nf = 0; nf < 4; nf++)                           \
        acc[4 + mf][nf] = mfma16(af2[mf], bfr[nf], acc[4 + mf][nf]);             \
    __builtin_amdgcn_s_setprio(0);                                               \
    __builtin_amdgcn_s_barrier();                                                \
    _Pragma("unroll") for (int x = 0; x < 4; x++) af[x] = RD_A(CB, 1, x);        \
    _Pragma("unroll") for (int x = 0; x < 4; x++) bfr[x] = RD_B(CB, 1, x);       \
    glds16(As0 + (K0N) + 32, dA + (NB) + 16384);                                 \
    glds16(As1 + (K0N) + 32, dA + (NB) + 16384 + 8192);                          \
    __builtin_amdgcn_s_barrier();                                                \
    asm volatile("s_waitcnt lgkmcnt(0)" ::: "memory");                           \
    __builtin_amdgcn_sched_barrier(0);                                           \
    __builtin_amdgcn_s_setprio(1);                                               \
    _Pragma("unroll") for (int mf = 0; mf < 4; mf++)                             \
      _Pragma("unroll") for (int nf = 0; nf < 4; nf++)                           \
        acc[mf][nf] = mfma16(af[mf], bfr[nf], acc[mf][nf]);                      \
    __builtin_amdgcn_s_setprio(0);                                               \
    __builtin_amdgcn_s_barrier();                                                \
    _Pragma("unroll") for (int x = 0; x < 4; x++) af2[x] = RD_A(CB, 1, 4 + x);   \
    glds16(Bs0 + (K0N) + 32, dB + (NB) + 16384);                                 \
    glds16(Bs1 + (K0N) + 32, dB + (NB) + 16384 + 8192);                          \
    asm volatile("s_waitcnt vmcnt(4)" ::: "memory");                             \
    __builtin_amdgcn_s_barrier();                                                \
    asm volatile("s_waitcnt lgkmcnt(0)" ::: "memory");                           \
    __builtin_amdgcn_sched_barrier(0);                                           \
    __builtin_amdgcn_s_setprio(1);                                               \
    _Pragma("unroll") for (int mf = 0; mf < 4; mf++)                             \
      _Pragma("unroll") for (int nf = 0; nf < 4; nf++)                           \
        acc[4 + mf][nf] = mfma16(af2[mf], bfr[nf], acc[4 + mf][nf]);             \
    __builtin_amdgcn_s_setprio(0);                                               \
    __builtin_amdgcn_s_barrier();                                                \
  }

template <int EPI>
__global__ __launch_bounds__(512, 2) void gemm256(const u16* __restrict__ A,
                                                  const u16* __restrict__ Bw,
                                                  void* __restrict__ Cout,
                                                  int M, int N, int K) {
  (void)M;
  __shared__ alignas(16) char lds[131072];
  const int tid = threadIdx.x;
  const int lane = tid & 63, wv = tid >> 6;
  const int wvm = wv >> 2, wvn = wv & 3;
  const int g = lane >> 4, l16 = lane & 15;

  // XCD-aware bijective block swizzle (nwg = 256, divisible by 8)
  const int gx = gridDim.x;
  const int nwg = gx * gridDim.y;
  const int lin = blockIdx.y * gx + blockIdx.x;
  const int swz = (lin & 7) * (nwg >> 3) + (lin >> 3);
  const int m0 = (swz / gx) * 256, n0 = (swz % gx) * 256;

  const int srow = tid >> 2;
  const int sg = (tid & 3) ^ ((srow >> 1) & 3);
  const u16* As0 = A + (size_t)(m0 + srow) * K + sg * 8;
  const u16* As1 = A + (size_t)(m0 + 128 + srow) * K + sg * 8;
  const u16* Bs0 = Bw + (size_t)(n0 + srow) * K + sg * 8;
  const u16* Bs1 = Bw + (size_t)(n0 + 128 + srow) * K + sg * 8;
  char* dA = lds + tid * 16;
  char* dB = lds + 65536 + tid * 16;

  const int rsw = (g ^ ((l16 >> 1) & 3)) << 4;
  const int rA = (wvm * 128 + l16) * 64 + rsw;
  const int rB = (wvn * 64 + l16) * 64 + rsw;

  f32x4 acc[8][4];
#pragma unroll
  for (int mf = 0; mf < 8; mf++)
#pragma unroll
    for (int nf = 0; nf < 4; nf++) acc[mf][nf] = (f32x4){0.f, 0.f, 0.f, 0.f};

  // prologue: stage tile 0 (h0 4 loads, then h1 4 loads); drain h0.
  glds16(As0, dA);
  glds16(As1, dA + 8192);
  glds16(Bs0, dB);
  glds16(Bs1, dB + 8192);
  glds16(As0 + 32, dA + 16384);
  glds16(As1 + 32, dA + 16384 + 8192);
  glds16(Bs0 + 32, dB + 16384);
  glds16(Bs1 + 32, dB + 16384 + 8192);
  asm volatile("s_waitcnt vmcnt(4)" ::: "memory");
  __builtin_amdgcn_s_barrier();

  const int NT = K >> 6;
  for (int t = 0; t < NT; t += 2) {
    const int kA = (t + 1) * 64;
    TILE256(0, 32768, kA)
    const int kB = (((t + 2) < NT) ? (t + 2) : 0) * 64;
    TILE256(32768, 0, kB)
  }

  if (EPI == 2) {
    u16* C = (u16*)Cout;
#pragma unroll
    for (int mf = 0; mf < 8; mf++) {
      int rowb = m0 + wvm * 128 + mf * 16 + g * 4;
#pragma unroll
      for (int nf = 0; nf < 4; nf++) {
        int col = n0 + wvn * 64 + nf * 16 + l16;
#pragma unroll
        for (int j = 0; j < 4; j++)
          C[(size_t)(rowb + j) * N + col] = f2bf(acc[mf][nf][j]);
      }
    }
  } else {  // EPI 1: V-transposed layout
    u16* C = (u16*)Cout;
#pragma unroll
    for (int mf = 0; mf < 8; mf++) {
      int rowb = m0 + wvm * 128 + mf * 16 + g * 4;
      int bb = rowb >> 11, tt = rowb & 2047;
#pragma unroll
      for (int nf = 0; nf < 4; nf++) {
        int col = n0 + wvn * 64 + nf * 16 + l16;
        uint64_t pk = (uint64_t)f2bf(acc[mf][nf][0]) |
                      ((uint64_t)f2bf(acc[mf][nf][1]) << 16) |
                      ((uint64_t)f2bf(acc[mf][nf][2]) << 32) |
                      ((uint64_t)f2bf(acc[mf][nf][3]) << 48);
        *(uint64_t*)(C + ((size_t)(bb * 4096 + col)) * 2048 + tt) = pk;
      }
    }
  }
}

// ============ 256x128 transposed-output GEMM, TRIPLE-buffered ============
// A = weights [4096][4096] (M-tiled by 256), Bact = activations [2048][4096]
// (N-tiled by 128). out[act][feature] written transposed vs accumulator.
// EPI 0: f32 out; EPI 2: bf16 out. Grid (16,16) = 256 blocks.
#define RD_AT(BUF, ks, mf) \
  (*(const bf16x8*)(lds + (BUF) * 32768 + (ks) * 16384 + (mf) * 1024 + rA))
#define RD_BT(BUF, ks, nf) \
  (*(const bf16x8*)(lds + 98304 + (BUF) * 16384 + (ks) * 8192 + (nf) * 1024 + rB))

#define STG_H0(BUF, K0N)                                    \
  glds16(AsT0 + (K0N), dAT + (BUF) * 32768);                \
  glds16(AsT1 + (K0N), dAT + (BUF) * 32768 + 8192);         \
  glds16(BsT0 + (K0N), dBT + (BUF) * 16384);

#define STG_H1(BUF, K0N)                                    \
  glds16(AsT0 + (K0N) + 32, dAT + (BUF) * 32768 + 16384);   \
  glds16(AsT1 + (K0N) + 32, dAT + (BUF) * 32768 + 16384 + 8192); \
  glds16(BsT0 + (K0N) + 32, dBT + (BUF) * 16384 + 8192);

#define TILE256T(CUR, STG, K0N)                                                  \
  {                                                                              \
    bf16x8 af[4], bfr[4];                                                        \
    _Pragma("unroll") for (int x = 0; x < 4; x++) af[x] = RD_AT(CUR, 0, x);      \
    _Pragma("unroll") for (int x = 0; x < 4; x++) bfr[x] = RD_BT(CUR, 0, x);     \
    STG_H0(STG, K0N)                                                             \
    __builtin_amdgcn_s_barrier();                                                \
    asm volatile("s_waitcnt lgkmcnt(0)" ::: "memory");                           \
    __builtin_amdgcn_sched_barrier(0);                                           \
    __builtin_amdgcn_s_setprio(1);                                               \
    _Pragma("unroll") for (int mf = 0; mf < 4; mf++)                             \
      _Pragma("unroll") for (int nf = 0; nf < 4; nf++)                           \
        acc[mf][nf] = mfma16(af[mf], bfr[nf], acc[mf][nf]);                      \
    __builtin_amdgcn_s_setprio(0);                                               \
    __builtin_amdgcn_s_barrier();                                                \
    _Pragma("unroll") for (int x = 0; x < 4; x++) af[x] = RD_AT(CUR, 1, x);      \
    _Pragma("unroll") for (int x = 0; x < 4; x++) bfr[x] = RD_BT(CUR, 1, x);     \
    STG_H1(STG, K0N)                                                             \
    asm volatile("s_waitcnt vmcnt(6)" ::: "memory");                             \
    __builtin_amdgcn_s_barrier();                                                \
    asm volatile("s_waitcnt lgkmcnt(0)" ::: "memory");                           \
    __builtin_amdgcn_sched_barrier(0);                                           \
    __builtin_amdgcn_s_setprio(1);                                               \
    _Pragma("unroll") for (int mf = 0; mf < 4; mf++)                             \
      _Pragma("unroll") for (int nf = 0; nf < 4; nf++)                           \
        acc[mf][nf] = mfma16(af[mf], bfr[nf], acc[mf][nf]);                      \
    __builtin_amdgcn_s_setprio(0);                                               \
    __builtin_amdgcn_s_barrier();                                                \
  }

template <int EPI>
__global__ __launch_bounds__(512, 2) void gemm256T(const u16* __restrict__ W,
                                                   const u16* __restrict__ Act,
                                                   void* __restrict__ Cout) {
  const int K = HID;       // NT = 64 = 21*3 + 1 tail
  __shared__ alignas(16) char lds[147456];
  const int tid = threadIdx.x;
  const int lane = tid & 63, wv = tid >> 6;
  const int wvm = wv >> 1, wvn = wv & 1;  // 4 x 2 waves, each 64x64
  const int g = lane >> 4, l16 = lane & 15;

  const int lin = blockIdx.y * 16 + blockIdx.x;
  const int swz = (lin & 7) * 32 + (lin >> 3);
  const int m0 = (swz >> 4) * 256;     // feature tile
  const int n0 = (swz & 15) * 128;     // activation tile

  const int srow = tid >> 2;
  const int sg = (tid & 3) ^ ((srow >> 1) & 3);
  const u16* AsT0 = W + (size_t)(m0 + srow) * K + sg * 8;
  const u16* AsT1 = W + (size_t)(m0 + 128 + srow) * K + sg * 8;
  const u16* BsT0 = Act + (size_t)(n0 + srow) * K + sg * 8;
  char* dAT = lds + tid * 16;
  char* dBT = lds + 98304 + tid * 16;

  const int rsw = (g ^ ((l16 >> 1) & 3)) << 4;
  const int rA = (wvm * 64 + l16) * 64 + rsw;
  const int rB = (wvn * 64 + l16) * 64 + rsw;

  f32x4 acc[4][4];
#pragma unroll
  for (int mf = 0; mf < 4; mf++)
#pragma unroll
    for (int nf = 0; nf < 4; nf++) acc[mf][nf] = (f32x4){0.f, 0.f, 0.f, 0.f};

  STG_H0(0, 0)
  STG_H1(0, 0)
  STG_H0(1, 64)
  STG_H1(1, 64)
  asm volatile("s_waitcnt vmcnt(6)" ::: "memory");
  __builtin_amdgcn_s_barrier();

  for (int t = 0; t < 63; t += 3) {
    const int k1 = (t + 2) * 64;
    const int k2 = (t + 3) * 64;
    const int k3 = ((t + 4) < 64) ? (t + 4) * 64 : 0;
    TILE256T(0, 2, k1)
    TILE256T(1, 0, k2)
    TILE256T(2, 1, k3)
  }
  {
    bf16x8 af[4], bfr[4];
#pragma unroll
    for (int x = 0; x < 4; x++) af[x] = RD_AT(0, 0, x);
#pragma unroll
    for (int x = 0; x < 4; x++) bfr[x] = RD_BT(0, 0, x);
#pragma unroll
    for (int mf = 0; mf < 4; mf++)
#pragma unroll
      for (int nf = 0; nf < 4; nf++)
        acc[mf][nf] = mfma16(af[mf], bfr[nf], acc[mf][nf]);
#pragma unroll
    for (int x = 0; x < 4; x++) af[x] = RD_AT(0, 1, x);
#pragma unroll
    for (int x = 0; x < 4; x++) bfr[x] = RD_BT(0, 1, x);
#pragma unroll
    for (int mf = 0; mf < 4; mf++)
#pragma unroll
      for (int nf = 0; nf < 4; nf++)
        acc[mf][nf] = mfma16(af[mf], bfr[nf], acc[mf][nf]);
  }

  if (EPI == 0) {
    float* C = (float*)Cout;
#pragma unroll
    for (int mf = 0; mf < 4; mf++) {
      int frow = m0 + wvm * 64 + mf * 16 + g * 4;
#pragma unroll
      for (int nf = 0; nf < 4; nf++) {
        int col = n0 + wvn * 64 + nf * 16 + l16;
        float4 v = {acc[mf][nf][0], acc[mf][nf][1], acc[mf][nf][2], acc[mf][nf][3]};
        *(float4*)(C + (size_t)col * HID + frow) = v;
      }
    }
  } else {
    u16* C = (u16*)Cout;
#pragma unroll
    for (int mf = 0; mf < 4; mf++) {
      int frow = m0 + wvm * 64 + mf * 16 + g * 4;
#pragma unroll
      for (int nf = 0; nf < 4; nf++) {
        int col = n0 + wvn * 64 + nf * 16 + l16;
        uint64_t pk = (uint64_t)f2bf(acc[mf][nf][0]) |
                      ((uint64_t)f2bf(acc[mf][nf][1]) << 16) |
                      ((uint64_t)f2bf(acc[mf][nf][2]) << 32) |
                      ((uint64_t)f2bf(acc[mf][nf][3]) << 48);
        *(uint64_t*)(C + (size_t)col * HID + frow) = pk;
      }
    }
  }
}

// ---------------- fused RoPE(Q) + RoPE(K) + vmean ----------------
// blocks [0,2048): Q rows; [2048,6144): K rows; [6144,8192): vmean
__device__ __forceinline__ void rope_row(const u16* x, float p, u16* out,
                                         int rowsPerB, int row, int t) {
  int b = row / rowsPerB, r = row - b * rowsPerB;
  int h = t >> 3, i0 = (t & 7) * 8;
  const u16* xr = x + (size_t)row * HID + h * HD;
  bf16x8 lov = *(const bf16x8*)(xr + i0);
  bf16x8 hiv = *(const bf16x8*)(xr + 64 + i0);
  union { u16 h[8]; bf16x8 v; } olo, ohi;
#pragma unroll
  for (int j = 0; j < 8; j++) {
    float lo = bf2f((u16)lov[j]);
    float hi = bf2f((u16)hiv[j]);
    float f = exp2f(-(float)(i0 + j) * (13.287712379549449f / 64.0f));
    float ang = p * f;
    float s, c;
    sincosf(ang, &s, &c);
    olo.h[j] = f2bf(lo * c - hi * s);
    ohi.h[j] = f2bf(hi * c + lo * s);
  }
  u16* ob = out + ((size_t)((b * NH + h) * rowsPerB) + r) * HD;
  *(bf16x8*)(ob + i0) = olo.v;
  *(bf16x8*)(ob + 64 + i0) = ohi.v;
}

__global__ __launch_bounds__(256) void rope_vmean_kernel(
    const u16* __restrict__ qsrc, const u16* __restrict__ ksrc,
    u16* __restrict__ qdst, u16* __restrict__ kdst,
    const int* __restrict__ pos, const int* __restrict__ tpos,
    const u16* __restrict__ vt, float* __restrict__ vm) {
  int bid = blockIdx.x;
  if (bid >= 6144) {
    int row = (bid - 6144) * 4 + (threadIdx.x >> 6);
    int lane = threadIdx.x & 63;
    const u16* p = vt + (size_t)row * KLEN;
    float s = 0.f;
#pragma unroll
    for (int it = 0; it < 4; it++) {
      bf16x8 v = *(const bf16x8*)(p + it * 512 + lane * 8);
#pragma unroll
      for (int j = 0; j < 8; j++) s += bf2f((u16)v[j]);
    }
    for (int off = 32; off; off >>= 1) s += __shfl_xor(s, off);
    if (lane == 0) vm[row] = s * (1.0f / (float)KLEN);
    return;
  }
  if (bid < 2048) {
    rope_row(qsrc, (float)pos[bid], qdst, QLEN, bid, threadIdx.x);
  } else {
    int row = bid - 2048;
    rope_row(ksrc, (float)tpos[row], kdst, KLEN, row, threadIdx.x);
  }
}

// ---------------- windowed flash attention ----------------
__global__ __launch_bounds__(256, 2) void attn_kernel(
    const u16* __restrict__ qb, const u16* __restrict__ kb,
    const u16* __restrict__ vt, const float* __restrict__ vm,
    const int* __restrict__ idxA, const int* __restrict__ wA,
    u16* __restrict__ aout) {
  __shared__ u16 Ks[32][136];
  __shared__ u16 Vs[128][40];
  __shared__ u16 Ps[4][16][40];
  __shared__ int sS[64], sE[64], sRange[2];

  const int tid = threadIdx.x, lane = tid & 63, wv = tid >> 6;
  const int g = lane >> 4, l16 = lane & 15;
  const int blk = blockIdx.x;
  const int qt = blk & 15, bh = blk >> 4, b = bh >> 5, h = bh & 31;
  const int q0 = qt * 64;
  const float SCALE = 0.08838834764831845f;

  if (tid < 64) {
    int e = idxA[b * QLEN + q0 + tid];
    int w = wA[b * QLEN + q0 + tid];
    int s = e - w;
    if (s < 0) s = 0;
    sS[tid] = s;
    sE[tid] = e;
  }
  __syncthreads();
  if (wv == 0) {
    int s_ = sS[lane], e_ = sE[lane];
    int mn = (e_ > s_) ? s_ : 0x7fffffff;
    int mx = (e_ > s_) ? e_ : 0;
    for (int off = 32; off; off >>= 1) {
      mn = min(mn, __shfl_xor(mn, off));
      mx = max(mx, __shfl_xor(mx, off));
    }
    if (lane == 0) { sRange[0] = mn; sRange[1] = mx; }
  }
  __syncthreads();
  const int klo = sRange[0], khi = sRange[1];

  int rs[4], re[4];
#pragma unroll
  for (int r = 0; r < 4; r++) {
    rs[r] = sS[wv * 16 + g * 4 + r];
    re[r] = sE[wv * 16 + g * 4 + r];
  }

  bf16x8 qf[4];
  {
    const u16* qp = qb + ((size_t)(bh * QLEN + q0 + wv * 16 + l16)) * HD + g * 8;
#pragma unroll
    for (int s4 = 0; s4 < 4; s4++) qf[s4] = *(const bf16x8*)(qp + s4 * 32);
  }

  f32x4 acc[8];
#pragma unroll
  for (int db = 0; db < 8; db++) acc[db] = (f32x4){0.f, 0.f, 0.f, 0.f};
  float mrow[4] = {-1e30f, -1e30f, -1e30f, -1e30f};
  float lsum[4] = {0.f, 0.f, 0.f, 0.f};

  if (klo < khi) {
    for (int t0 = (klo & ~31); t0 < khi; t0 += 32) {
      {
        int idx = tid * 8;
        int kr = idx >> 7, kc = idx & 127;
        *(bf16x8*)(&Ks[kr][kc]) =
            *(const bf16x8*)(kb + ((size_t)(bh * KLEN + t0 + kr)) * HD + kc);
        int kr2 = kr + 16;
        *(bf16x8*)(&Ks[kr2][kc]) =
            *(const bf16x8*)(kb + ((size_t)(bh * KLEN + t0 + kr2)) * HD + kc);
        int vr = idx >> 5, vc = idx & 31;
        *(bf16x8*)(&Vs[vr][vc]) =
            *(const bf16x8*)(vt + ((size_t)(bh * HD + vr)) * KLEN + t0 + vc);
        int vr2 = vr + 64;
        *(bf16x8*)(&Vs[vr2][vc]) =
            *(const bf16x8*)(vt + ((size_t)(bh * HD + vr2)) * KLEN + t0 + vc);
      }
      __syncthreads();

      f32x4 sc0 = (f32x4){0.f, 0.f, 0.f, 0.f};
      f32x4 sc1 = (f32x4){0.f, 0.f, 0.f, 0.f};
#pragma unroll
      for (int s4 = 0; s4 < 4; s4++) {
        bf16x8 k0 = *(const bf16x8*)(&Ks[l16][s4 * 32 + g * 8]);
        bf16x8 k1 = *(const bf16x8*)(&Ks[16 + l16][s4 * 32 + g * 8]);
        sc0 = mfma16(qf[s4], k0, sc0);
        sc1 = mfma16(qf[s4], k1, sc1);
      }

      float resc[4];
#pragma unroll
      for (int r = 0; r < 4; r++) {
        float v0 = sc0[r] * SCALE, v1 = sc1[r] * SCALE;
        int t_0 = t0 + l16, t_1 = t0 + 16 + l16;
        v0 = (t_0 >= rs[r] && t_0 < re[r]) ? v0 : -1e30f;
        v1 = (t_1 >= rs[r] && t_1 < re[r]) ? v1 : -1e30f;
        float mx = fmaxf(v0, v1);
        mx = fmaxf(mx, __shfl_xor(mx, 1));
        mx = fmaxf(mx, __shfl_xor(mx, 2));
        mx = fmaxf(mx, __shfl_xor(mx, 4));
        mx = fmaxf(mx, __shfl_xor(mx, 8));
        float mn = fmaxf(mrow[r], mx);
        float rc = __expf(mrow[r] - mn);
        float p0 = __expf(v0 - mn), p1 = __expf(v1 - mn);
        mrow[r] = mn;
        resc[r] = rc;
        float ps = p0 + p1;
        ps += __shfl_xor(ps, 1);
        ps += __shfl_xor(ps, 2);
        ps += __shfl_xor(ps, 4);
        ps += __shfl_xor(ps, 8);
        lsum[r] = lsum[r] * rc + ps;
        Ps[wv][g * 4 + r][l16] = f2bf(p0);
        Ps[wv][g * 4 + r][16 + l16] = f2bf(p1);
      }
#pragma unroll
      for (int db = 0; db < 8; db++) {
#pragma unroll
        for (int r = 0; r < 4; r++) acc[db][r] *= resc[r];
      }
      bf16x8 pf = *(const bf16x8*)(&Ps[wv][l16][g * 8]);
#pragma unroll
      for (int db = 0; db < 8; db++) {
        bf16x8 vf = *(const bf16x8*)(&Vs[db * 16 + l16][g * 8]);
        acc[db] = mfma16(pf, vf, acc[db]);
      }
      __syncthreads();
    }
  }

#pragma unroll
  for (int r = 0; r < 4; r++) {
    int lr = wv * 16 + g * 4 + r;
    int q = q0 + lr;
    bool empty = (re[r] <= rs[r]);
    float inv = empty ? 0.f : 1.0f / lsum[r];
    u16* orow = aout + ((size_t)(b * QLEN + q)) * HID + h * HD;
#pragma unroll
    for (int db = 0; db < 8; db++) {
      float o = empty ? vm[bh * HD + db * 16 + l16] : acc[db][r] * inv;
      orow[db * 16 + l16] = f2bf(o);
    }
  }
}

// ---------------- host ----------------
extern "C" void kernel_launch(void* const* d_in, const int* in_sizes, int n_in,
                              void* d_out, int out_size, void* d_ws, size_t ws_size,
                              hipStream_t stream) {
  (void)in_sizes; (void)n_in; (void)out_size; (void)ws_size;
  const float* hs = (const float*)d_in[0];
  const float* kvs = (const float*)d_in[1];
  const float* Wq = (const float*)d_in[2];
  const float* Wk = (const float*)d_in[3];
  const float* Wv = (const float*)d_in[4];
  const float* Wo = (const float*)d_in[5];
  const int* pos = (const int*)d_in[6];
  const int* tpos = (const int*)d_in[7];
  const int* sidx = (const int*)d_in[8];
  const int* wsz = (const int*)d_in[9];
  float* out = (float*)d_out;

  char* ws = (char*)d_ws;
  size_t off = 0;
  auto alloc = [&](size_t bytes) -> void* {
    void* p = ws + off;
    off += (bytes + 255) & ~(size_t)255;
    return p;
  };
  const size_t WN = (size_t)HID * HID;           // 16.78M elems
  const size_t NQ = (size_t)BATCH * QLEN * HID;  // 8.39M
  const size_t NK = (size_t)BATCH * KLEN * HID;  // 16.78M

  // ~252 MB total
  u16* w1 = (u16*)alloc(WN * 2);   // Wk, then Wq, then Wo
  u16* w2 = (u16*)alloc(WN * 2);   // Wv
  u16* hid_b = (u16*)alloc(NQ * 2);
  u16* kv_b = (u16*)alloc(NK * 2);
  u16* sc_b = (u16*)alloc(NK * 2);       // K-proj out, later attn out
  u16* qp_b = (u16*)alloc(NQ * 2);       // Q-proj out
  u16* q_b = (u16*)alloc(NQ * 2);
  u16* k_b = (u16*)alloc(NK * 2);
  u16* vt_b = (u16*)alloc(NK * 2);
  float* vmean = (float*)alloc((size_t)BATCH * NH * HD * 4);

  // 1. both activations -> bf16
  cvt2_kernel<<<(int)((NQ + NK) / 2048), 256, 0, stream>>>(hs, hid_b, (int)NQ,
                                                           kvs, kv_b, (int)NK);
  // 2. Wk + Wv -> bf16
  cvt2_kernel<<<(int)(2 * WN / 2048), 256, 0, stream>>>(Wk, w1, (int)WN,
                                                        Wv, w2, (int)WN);
  // 3. K projection (256^2) -> bf16 row-major sc_b
  gemm256<2><<<dim3(16, 16), 512, 0, stream>>>(kv_b, w1, sc_b,
                                               BATCH * KLEN, HID, HID);
  // 4. V projection (256^2) -> VT layout
  gemm256<1><<<dim3(16, 16), 512, 0, stream>>>(kv_b, w2, vt_b,
                                               BATCH * KLEN, HID, HID);
  // 5-6. Q projection (w1 reusable after step 3)
  cvt_kernel<<<(int)(WN / 2048), 256, 0, stream>>>(Wq, w1, (int)WN);
  gemm256T<2><<<dim3(16, 16), 512, 0, stream>>>(w1, hid_b, qp_b);

  // 7. RoPE(Q) + RoPE(K) + vmean
  rope_vmean_kernel<<<8192, 256, 0, stream>>>(qp_b, sc_b, q_b, k_b, pos, tpos,
                                              vt_b, vmean);

  // 8. attention -> bf16 [B,Q,HID] into sc_b
  attn_kernel<<<BATCH * NH * (QLEN / 64), 256, 0, stream>>>(
      q_b, k_b, vt_b, vmean, sidx, wsz, sc_b);

  // 9-10. output projection -> f32 d_out
  cvt_kernel<<<(int)(WN / 2048), 256, 0, stream>>>(Wo, w1, (int)WN);
  gemm256T<0><<<dim3(16, 16), 512, 0, stream>>>(w1, sc_b, out);
}